// Round 12
// baseline (68.046 us; speedup 1.0000x reference)
//
#include <hip/hip_runtime.h>

#define NQ 10

// Split-statevector layout: basis index e in [0,1024), qubit q at bit (9-q).
//   lane   = e & 63        (bits 5..0 = qubits 4..9)
//   wave w = bit 9 (rb3)   (qubit 0)  -> 2 waves per batch element
//   reg  j = bits 8..6     (rb2,rb1,rb0 = qubits 1..3), v2f v[8] per lane.
// 4096 waves total = 16 waves/CU = 4/SIMD (2x round-11 occupancy).
//
// Cross-lane primitives: exactly the round-10/11 PASSING set.
//   xor1 -> DPP quad_perm 0xB1, xor2 -> 0x4E, xor8 -> row_ror:8 (0x128)
//   xor4 -> ds_swizzle 0x101F, xor16 -> ds_swizzle 0x401F
//   xor32 + composed CNOT gather -> ds_bpermute
// Cross-wave (wrap CNOT + RY-q0, adjacent ops) fused into ONE LDS exchange
// per layer; 4 barriers total.

typedef float v2f __attribute__((ext_vector_type(2)));

template<int CTRL>
__device__ __forceinline__ float dppf(float v) {
    const int i = __float_as_int(v);
    const int r = __builtin_amdgcn_update_dpp(i, i, CTRL, 0xF, 0xF, false);
    return __int_as_float(r);
}
template<int OFF>
__device__ __forceinline__ float swzf(float v) {
    return __int_as_float(__builtin_amdgcn_ds_swizzle(__float_as_int(v), OFF));
}
__device__ __forceinline__ float bpermf(int addr4, float v) {
    return __int_as_float(__builtin_amdgcn_ds_bpermute(addr4, __float_as_int(v)));
}
__device__ __forceinline__ float rdlane(float v, int l) {
    return __int_as_float(__builtin_amdgcn_readlane(__float_as_int(v), l));
}
__device__ __forceinline__ v2f splat(float a) { v2f r; r.x = a; r.y = a; return r; }
__device__ __forceinline__ v2f cmul(v2f a, v2f b) {
    v2f r;
    r.x = a.x * b.x - a.y * b.y;
    r.y = a.x * b.y + a.y * b.x;
    return r;
}

__global__ __launch_bounds__(128) void qnn_kernel(const float* __restrict__ x,
                                                  const float* __restrict__ w,
                                                  float* __restrict__ out,
                                                  int B) {
    const int tid  = threadIdx.x;
    const int lane = tid & 63;
    const int wv   = tid >> 6;       // 0/1 = this wave's rb3 (qubit 0) value
    const int b    = blockIdx.x;

    __shared__ v2f  xch[2][2][8][64];   // [buf][wave][reg][lane]
    __shared__ float red[NQ];

    // ---- angle tables: lanes 0..9 RX(x), lanes 0..39 RY weights ----
    float cxv = 1.f, sxv = 0.f, cwv = 1.f, swv = 0.f;
    if (lane < NQ) {
        const float a = 0.5f * x[b * NQ + lane];
        cxv = cosf(a); sxv = sinf(a);
    }
    if (lane < 4 * NQ) {
        const float a = 0.5f * w[lane];
        cwv = cosf(a); swv = sinf(a);
    }

    // ---- per-qubit 2-vectors after RX(x_q) then layer-0 RY(w0_q) ----
    // u0 = (ch*c, sh*s), u1 = (sh*c, -ch*s)
    v2f u0[NQ], u1[NQ];
#pragma unroll
    for (int q = 0; q < NQ; ++q) {
        const float c  = rdlane(cxv, q), s  = rdlane(sxv, q);
        const float ch = rdlane(cwv, q), sh = rdlane(swv, q);
        u0[q].x = ch * c;  u0[q].y = sh * s;
        u1[q].x = sh * c;  u1[q].y = -ch * s;
    }

    // ---- product state (this wave's half: rb3 = wv) ----
    v2f ml = (lane & 1) ? u1[9] : u0[9];            // lane bit p = qubit 9-p
#pragma unroll
    for (int p = 1; p < 6; ++p) {
        const v2f f = ((lane >> p) & 1) ? u1[9 - p] : u0[9 - p];
        ml = cmul(ml, f);
    }
    const v2f f0 = wv ? u1[0] : u0[0];              // qubit 0 factor (fixed)
    v2f t01[2] = { cmul(f0, u0[1]), cmul(f0, u1[1]) };   // qubit 1 = j bit2
    v2f m01[4];
#pragma unroll
    for (int j = 0; j < 4; ++j) {                   // j bit0=qubit3, bit1=qubit2
        m01[j] = cmul((j & 1) ? u1[3] : u0[3], (j & 2) ? u1[2] : u0[2]);
    }
    v2f v[8];
#pragma unroll
    for (int j = 0; j < 8; ++j) v[j] = cmul(cmul(ml, t01[j >> 2]), m01[j & 3]);

    // composed source lane for the q=4..8 CNOT chain; sigma_{q=3} folded:
    // odd regs (rb0=1) gather from srcl^32.
    int t = lane;
    t ^= ((t >> 1) & 1) << 0;   // sigma_{q=8}
    t ^= ((t >> 2) & 1) << 1;   // q=7
    t ^= ((t >> 3) & 1) << 2;   // q=6
    t ^= ((t >> 4) & 1) << 3;   // q=5
    t ^= ((t >> 5) & 1) << 4;   // q=4
    const int ga4 = t << 2;
    const int gb4 = (t ^ 32) << 2;
    const int a32 = (lane ^ 32) << 2;
    const bool odd = (lane & 1);    // wrap CNOT ctrl = qubit 9

    // ---- 3x { CNOT ring ; RY sweep(layer l+1) } ----
#pragma unroll
    for (int l = 0; l < 3; ++l) {
        // -- ring q0 (ctrl rb3, tgt rb2): only the rb3=1 wave renames --
        if (wv) {
            v2f tmp;
            tmp = v[0]; v[0] = v[4]; v[4] = tmp;
            tmp = v[1]; v[1] = v[5]; v[5] = tmp;
            tmp = v[2]; v[2] = v[6]; v[6] = tmp;
            tmp = v[3]; v[3] = v[7]; v[7] = tmp;
        }
        // -- ring q1 (ctrl rb2, tgt rb1) --
        { v2f tmp;
          tmp = v[4]; v[4] = v[6]; v[6] = tmp;
          tmp = v[5]; v[5] = v[7]; v[7] = tmp; }
        // -- ring q2 (ctrl rb1, tgt rb0) --
        { v2f tmp;
          tmp = v[2]; v[2] = v[3]; v[3] = tmp;
          tmp = v[6]; v[6] = v[7]; v[7] = tmp; }
        // -- ring q3..q8 fused gather --
#pragma unroll
        for (int j = 0; j < 8; ++j) {
            const int a4 = (j & 1) ? gb4 : ga4;
            v[j].x = bpermf(a4, v[j].x);
            v[j].y = bpermf(a4, v[j].y);
        }
        // -- fused wrap (ctrl lane bit0, tgt rb3) + RY q0 (pairs rb3) --
        const int base = (l + 1) * NQ;
        const int buf = l & 1;
#pragma unroll
        for (int j = 0; j < 8; ++j) xch[buf][wv][j][lane] = v[j];
        __syncthreads();
        {
            const float c = rdlane(cwv, base + 0);
            const float s = rdlane(swv, base + 0);
            const v2f C = splat(c);
            const v2f S = splat(wv ? s : -s);
#pragma unroll
            for (int j = 0; j < 8; ++j) {
                const v2f u2 = xch[buf][wv ^ 1][j][lane];
                const v2f mine = odd ? u2 : v[j];
                const v2f part = odd ? v[j] : u2;
                v[j] = C * mine + S * part;
            }
        }
        // -- RY q1..q3 (reg-local: m = 4,2,1) --
#pragma unroll
        for (int q = 1; q < 4; ++q) {
            const v2f C = splat(rdlane(cwv, base + q));
            const v2f S = splat(rdlane(swv, base + q));
            const int m = 1 << (3 - q);
#pragma unroll
            for (int j = 0; j < 8; ++j) {
                if (!(j & m)) {
                    const int j1 = j | m;
                    const v2f a0 = v[j], a1 = v[j1];
                    v[j]  = C * a0 - S * a1;
                    v[j1] = S * a0 + C * a1;
                }
            }
        }
        // -- q4 (xor32): ds_bpermute --
        {
            const float c = rdlane(cwv, base + 4);
            const float s = rdlane(swv, base + 4);
            const v2f C = splat(c);
            const v2f SS = splat((lane & 32) ? s : -s);
#pragma unroll
            for (int j = 0; j < 8; ++j) {
                v2f o; o.x = bpermf(a32, v[j].x); o.y = bpermf(a32, v[j].y);
                v[j] = C * v[j] + SS * o;
            }
        }
        // -- q5 (xor16): ds_swizzle 0x401F --
        {
            const float c = rdlane(cwv, base + 5);
            const float s = rdlane(swv, base + 5);
            const v2f C = splat(c);
            const v2f SS = splat((lane & 16) ? s : -s);
#pragma unroll
            for (int j = 0; j < 8; ++j) {
                v2f o; o.x = swzf<0x401F>(v[j].x); o.y = swzf<0x401F>(v[j].y);
                v[j] = C * v[j] + SS * o;
            }
        }
        // -- q6 (xor8): DPP row_ror:8 --
        {
            const float c = rdlane(cwv, base + 6);
            const float s = rdlane(swv, base + 6);
            const v2f C = splat(c);
            const v2f SS = splat((lane & 8) ? s : -s);
#pragma unroll
            for (int j = 0; j < 8; ++j) {
                v2f o; o.x = dppf<0x128>(v[j].x); o.y = dppf<0x128>(v[j].y);
                v[j] = C * v[j] + SS * o;
            }
        }
        // -- q7 (xor4): ds_swizzle 0x101F --
        {
            const float c = rdlane(cwv, base + 7);
            const float s = rdlane(swv, base + 7);
            const v2f C = splat(c);
            const v2f SS = splat((lane & 4) ? s : -s);
#pragma unroll
            for (int j = 0; j < 8; ++j) {
                v2f o; o.x = swzf<0x101F>(v[j].x); o.y = swzf<0x101F>(v[j].y);
                v[j] = C * v[j] + SS * o;
            }
        }
        // -- q8 (xor2): DPP quad_perm [2,3,0,1] --
        {
            const float c = rdlane(cwv, base + 8);
            const float s = rdlane(swv, base + 8);
            const v2f C = splat(c);
            const v2f SS = splat((lane & 2) ? s : -s);
#pragma unroll
            for (int j = 0; j < 8; ++j) {
                v2f o; o.x = dppf<0x4E>(v[j].x); o.y = dppf<0x4E>(v[j].y);
                v[j] = C * v[j] + SS * o;
            }
        }
        // -- q9 (xor1): DPP quad_perm [1,0,3,2] --
        {
            const float c = rdlane(cwv, base + 9);
            const float s = rdlane(swv, base + 9);
            const v2f C = splat(c);
            const v2f SS = splat((lane & 1) ? s : -s);
#pragma unroll
            for (int j = 0; j < 8; ++j) {
                v2f o; o.x = dppf<0xB1>(v[j].x); o.y = dppf<0xB1>(v[j].y);
                v[j] = C * v[j] + SS * o;
            }
        }
    }

    // ---- measurement, ring-3 folded into signs (r11 mapping, split by w) ----
    float T7 = 0.f, T4 = 0.f, T6 = 0.f;
#pragma unroll
    for (int j = 0; j < 8; ++j) {
        const float pj = v[j].x * v[j].x + v[j].y * v[j].y;
        T7 += (__popc(j) & 1)     ? -pj : pj;
        T4 += (j & 4)             ? -pj : pj;
        T6 += (__popc(j & 6) & 1) ? -pj : pj;
    }
    const float sw   = wv ? -1.f : 1.f;                    // rb3 in mask
    const float gAll = (__popc(lane) & 1) ? -1.f : 1.f;
    const float W7 = sw * T7;
    float acc[NQ];
    acc[0] = gAll * T7;
    acc[1] = sw * T4;
    acc[2] = sw * T6;
    acc[3] = W7;
    acc[4] = ((lane >> 5) & 1) ? -W7 : W7;
    acc[5] = (__popc(lane & 0x30) & 1) ? -W7 : W7;
    acc[6] = (__popc(lane & 0x38) & 1) ? -W7 : W7;
    acc[7] = (__popc(lane & 0x3C) & 1) ? -W7 : W7;
    acc[8] = (__popc(lane & 0x3E) & 1) ? -W7 : W7;
    acc[9] = gAll * W7;

    // 64-lane reduce per qubit: bperm (xor32) + swizzle/DPP butterfly
#pragma unroll
    for (int q = 0; q < NQ; ++q) {
        float a = acc[q];
        a += bpermf(a32, a);
        a += swzf<0x401F>(a);
        a += dppf<0x128>(a);
        a += swzf<0x101F>(a);
        a += dppf<0x4E>(a);
        a += dppf<0xB1>(a);
        acc[q] = a;
    }
    // cross-wave combine
    if (wv == 1 && lane == 0) {
#pragma unroll
        for (int q = 0; q < NQ; ++q) red[q] = acc[q];
    }
    __syncthreads();
    if (wv == 0 && lane == 0) {
#pragma unroll
        for (int q = 0; q < NQ; ++q) out[b * NQ + q] = acc[q] + red[q];
    }
}

extern "C" void kernel_launch(void* const* d_in, const int* in_sizes, int n_in,
                              void* d_out, int out_size, void* d_ws, size_t ws_size,
                              hipStream_t stream) {
    const float* x = (const float*)d_in[0];   // [B, 10]
    const float* w = (const float*)d_in[1];   // [40]
    float* out = (float*)d_out;               // [B, 10]
    const int B = in_sizes[0] / NQ;           // 2048
    qnn_kernel<<<B, 128, 0, stream>>>(x, w, out, B);
}